// Round 4
// baseline (2287.206 us; speedup 1.0000x reference)
//
#include <hip/hip_runtime.h>
#include <math.h>

// Problem constants (reference: T=16384, H=2048, E=256)
#define H_      2048
#define E_      256
#define T_TILE  32      // tokens per block (8 per wave, 4 waves) -> grid 512
#define KC      32      // K-chunk staged in LDS (2 SSE 16-blocks)
#define TOPK    8
#define KGROUP  4

typedef float f2 __attribute__((ext_vector_type(2)));

// LDS (double-buffered, T3-minimum 2-phase schedule):
//  w[2][E][KC]: expert-major, slot-swizzled at float4 granularity: stored
//    slot s of row e holds global float4-slot s^((e>>2)&7). Staged by
//    global_load_lds (linear dest) with pre-swizzled SOURCE addresses
//    (both-sides-or-neither); read-side ds_read_b128 applies the same XOR.
//  h[2][T_TILE][KC]: linear; compute reads are SAME-ADDRESS ds_read_b128
//    broadcasts (conflict-free, zero VALU).
// Schedule per chunk: STAGE(next buf) issued FIRST, then compute(cur buf),
// then ONE __syncthreads. The compiler's vmcnt(0)-before-barrier drain is
// harmless: the staged loads have been in flight for the whole compute
// phase (~2500 cy >> L2 latency). Buffer indices are compile-time constants
// (loop unrolled x2) so the compiler can statically disambiguate w[0]/w[1]
// and never serializes stage-issue against ds_read of the other buffer.
struct GemmSmem {
    float w[2][E_][KC];      // 65536 B
    float h[2][T_TILE][KC];  //  8192 B
};
union SMem {
    GemmSmem g;
    float logits[T_TILE][E_];   // 32768 B
};

__global__ __launch_bounds__(256, 2)
void router_kernel(const float* __restrict__ hp,
                   const float* __restrict__ wp,
                   const float* __restrict__ bp,
                   float* __restrict__ out, int T)
{
#pragma clang fp contract(off)
    __shared__ SMem sm;
    const int tid  = threadIdx.x;
    const int t0   = blockIdx.x * T_TILE;
    const int lane = tid & 63;
    const int eq   = lane;          // expert quad: experts eq*4 .. eq*4+3
    const int wv   = tid >> 6;      // wave id: tokens wv*8 .. wv*8+7
    const int wvu  = __builtin_amdgcn_readfirstlane(wv);

    // numpy einsum sum_of_products emulation: per output, 4 independent
    // mod-4 chains (l = k%4), adds per 16-block in j-desc order, all mul/add
    // UNFUSED fp32. Chains packed in f2 pairs (l0,l1)/(l2,l3) -> v_pk_* ok
    // (IEEE-identical per component).
    f2 acc[8][4][2];   // [token i][expert j][pair]
#pragma unroll
    for (int i = 0; i < 8; ++i)
#pragma unroll
        for (int j = 0; j < 4; ++j) {
            acc[i][j][0] = (f2){0.f, 0.f};
            acc[i][j][1] = (f2){0.f, 0.f};
        }

    const int swx = eq & 7;            // read-side XOR key = (e>>2)&7

    // ---- stage chunk CH into buffer B: 1 h wave-op + 8 w wave-ops x 1024B.
#define STAGE(B, CH) do {                                                     \
        const int k0s = (CH) * KC;                                            \
        {   const float* srcH = hp                                            \
                + (size_t)(t0 + (wvu << 3) + (lane >> 3)) * H_                \
                + k0s + ((lane & 7) << 2);                                    \
            __builtin_amdgcn_global_load_lds(                                 \
                (const __attribute__((address_space(1))) void*)srcH,          \
                (__attribute__((address_space(3))) void*)&sm.g.h[B][wvu<<3][0],\
                16, 0, 0); }                                                  \
        _Pragma("unroll")                                                     \
        for (int r = 0; r < 8; ++r) {                                         \
            const int E0 = (r * 4 + wvu) * 8;                                 \
            const int e  = E0 + (lane >> 3);                                  \
            const int gs = (lane & 7) ^ ((e >> 2) & 7);                       \
            const float* srcW = wp + (size_t)e * H_ + k0s + (gs << 2);        \
            __builtin_amdgcn_global_load_lds(                                 \
                (const __attribute__((address_space(1))) void*)srcW,          \
                (__attribute__((address_space(3))) void*)&sm.g.w[B][E0][0],   \
                16, 0, 0); }                                                  \
    } while (0)

    // ---- compute one chunk from buffer B: 16-blocks ascending (mb),
    // j-group descending (jj); identical global k-block order.
#define COMPUTE(B) do {                                                       \
        _Pragma("unroll")                                                     \
        for (int mb = 0; mb < 2; ++mb) {                                      \
            _Pragma("unroll")                                                 \
            for (int jj = 3; jj >= 0; --jj) {                                 \
                const int S = (mb << 2) + jj;      /* global float4-slot */   \
                const float* wr = &sm.g.w[B][eq << 2][(S ^ swx) << 2];        \
                float4 wreg[4];                                               \
                wreg[0] = *(const float4*)(wr);                               \
                wreg[1] = *(const float4*)(wr + KC);                          \
                wreg[2] = *(const float4*)(wr + 2 * KC);                      \
                wreg[3] = *(const float4*)(wr + 3 * KC);                      \
                _Pragma("unroll")                                             \
                for (int i = 0; i < 8; ++i) {                                 \
                    const float4 hv = *(const float4*)                        \
                        (&sm.g.h[B][(wvu << 3) + i][S << 2]);                 \
                    const f2 hA = {hv.x, hv.y};   /* chains l=0,1 */          \
                    const f2 hB = {hv.z, hv.w};   /* chains l=2,3 */          \
                    _Pragma("unroll")                                         \
                    for (int j = 0; j < 4; ++j) {                             \
                        const f2 wA = {wreg[j].x, wreg[j].y};                 \
                        const f2 wB = {wreg[j].z, wreg[j].w};                 \
                        f2 pA = hA * wA;                  /* unfused mul */   \
                        f2 pB = hB * wB;                                      \
                        acc[i][j][0] = acc[i][j][0] + pA; /* unfused add */   \
                        acc[i][j][1] = acc[i][j][1] + pB;                     \
                    }                                                         \
                }                                                             \
            }                                                                 \
        }                                                                     \
    } while (0)

    // ---- prologue: stage chunk 0 into buffer 0
    STAGE(0, 0);
    __syncthreads();                 // vmcnt(0) drain (exposed once)

    // ---- main loop: 64 chunks, unrolled x2 for static buffer indices
    for (int ch2 = 0; ch2 < 32; ++ch2) {
        const int chA = 2 * ch2;
        // phase A: stage chA+1 -> buf1, compute chA from buf0
        STAGE(1, chA + 1);
        COMPUTE(0);
        __syncthreads();             // staged loads long since landed
        // phase B: stage chA+2 -> buf0 (unless done), compute chA+1 from buf1
        if (ch2 < 31) STAGE(0, chA + 2);
        COMPUTE(1);
        __syncthreads();
    }
#undef STAGE
#undef COMPUTE

    // ---- hadd tree (v0+v1)+(v2+v3) + dump fp32 logits into unioned tile
#pragma unroll
    for (int i = 0; i < 8; ++i)
#pragma unroll
        for (int j = 0; j < 4; ++j)
            sm.logits[(wv << 3) + i][(eq << 2) + j] =
                ((acc[i][j][0].x + acc[i][j][0].y) +
                 (acc[i][j][1].x + acc[i][j][1].y));
    __syncthreads();

    // ================= routing: each wave handles its 8 tokens ==============
    float* out_idx = out;                       // [T][8] indices as floats
    float* out_w   = out + (size_t)T * TOPK;    // [T][8] weights

    const float b0 = bp[lane * 4 + 0];
    const float b1 = bp[lane * 4 + 1];
    const float b2 = bp[lane * 4 + 2];
    const float b3 = bp[lane * 4 + 3];

    for (int tt = 0; tt < 8; ++tt) {
        const int tl = (wv << 3) + tt;
        const int t  = t0 + tl;

        float4 lg = *(const float4*)(&sm.logits[tl][lane * 4]);
        // numpy graph: s = 1/(1+exp(-x)), fp32 add + fp32 division;
        // exp in fp64, correctly rounded to fp32.
        const float E0 = (float)exp(-(double)lg.x);
        const float E1 = (float)exp(-(double)lg.y);
        const float E2 = (float)exp(-(double)lg.z);
        const float E3 = (float)exp(-(double)lg.w);
        const float s0 = __fdiv_rn(1.0f, __fadd_rn(1.0f, E0));
        const float s1 = __fdiv_rn(1.0f, __fadd_rn(1.0f, E1));
        const float s2 = __fdiv_rn(1.0f, __fadd_rn(1.0f, E2));
        const float s3 = __fdiv_rn(1.0f, __fadd_rn(1.0f, E3));
        // scores_for_choice = score + bias (fp32 add; bias == 0)
        const float f0 = s0 + b0, f1 = s1 + b1, f2 = s2 + b2, f3 = s3 + b3;

        // ---- per-lane top-2 of its 4 sfc values
        float a = fmaxf(f0, f1), b = fminf(f0, f1);
        if (f2 > a) { b = a; a = f2; } else b = fmaxf(b, f2);
        if (f3 > a) { b = a; a = f3; } else b = fmaxf(b, f3);
        // ---- reduce top-2 across the 8 lanes of this group
#pragma unroll
        for (int m = 1; m <= 4; m <<= 1) {
            float oa = __shfl_xor(a, m);
            float ob = __shfl_xor(b, m);
            float na, nb;
            if (a >= oa) { na = a;  nb = fmaxf(oa, b); }
            else         { na = oa; nb = fmaxf(a, ob); }
            a = na; b = nb;
        }
        const float gsc = a + b;   // group score (fp32)

        // gather all 8 group scores to every lane
        float g0 = __shfl(gsc,  0), g1 = __shfl(gsc,  8);
        float g2 = __shfl(gsc, 16), g3 = __shfl(gsc, 24);
        float g4 = __shfl(gsc, 32), g5 = __shfl(gsc, 40);
        float g6 = __shfl(gsc, 48), g7 = __shfl(gsc, 56);

        // ---- top-4 groups (stable: lower index wins ties via strict >)
        unsigned gmask = 0;
#pragma unroll
        for (int r = 0; r < KGROUP; ++r) {
            float best = g0; int bg = 0;
            if (g1 > best) { best = g1; bg = 1; }
            if (g2 > best) { best = g2; bg = 2; }
            if (g3 > best) { best = g3; bg = 3; }
            if (g4 > best) { best = g4; bg = 4; }
            if (g5 > best) { best = g5; bg = 5; }
            if (g6 > best) { best = g6; bg = 6; }
            if (g7 > best) { best = g7; bg = 7; }
            gmask |= (1u << bg);
            g0 = (bg == 0) ? -1.f : g0;  g1 = (bg == 1) ? -1.f : g1;
            g2 = (bg == 2) ? -1.f : g2;  g3 = (bg == 3) ? -1.f : g3;
            g4 = (bg == 4) ? -1.f : g4;  g5 = (bg == 5) ? -1.f : g5;
            g6 = (bg == 6) ? -1.f : g6;  g7 = (bg == 7) ? -1.f : g7;
        }

        // ---- masked sfc (unselected groups -> 0.0, matching np.where)
        const int  myg  = lane >> 3;
        const bool keep = (gmask >> myg) & 1u;
        float v0 = keep ? f0 : 0.f, v1 = keep ? f1 : 0.f;
        float v2 = keep ? f2 : 0.f, v3 = keep ? f3 : 0.f;

        // ---- top-8: 8 rounds of 64-lane butterfly argmax, fp32 values,
        //      exact-equality ties -> lower expert index (stable top_k)
        int   isel[TOPK];
        float ssel[TOPK];
#pragma unroll
        for (int r = 0; r < TOPK; ++r) {
            float bv = v0; int bj = 0; float bs = s0;
            if (v1 > bv) { bv = v1; bj = 1; bs = s1; }
            if (v2 > bv) { bv = v2; bj = 2; bs = s2; }
            if (v3 > bv) { bv = v3; bj = 3; bs = s3; }
            float cv = bv; int ci = lane * 4 + bj; float cs = bs;
#pragma unroll
            for (int m = 1; m < 64; m <<= 1) {
                float ov = __shfl_xor(cv, m);
                int   oi = __shfl_xor(ci, m);
                float os = __shfl_xor(cs, m);
                if (ov > cv || (ov == cv && oi < ci)) { cv = ov; ci = oi; cs = os; }
            }
            isel[r] = ci; ssel[r] = cs;
            if ((ci >> 2) == lane) {       // owner removes the winner
                const int sl = ci & 3;
                v0 = (sl == 0) ? -1.f : v0;
                v1 = (sl == 1) ? -1.f : v1;
                v2 = (sl == 2) ? -1.f : v2;
                v3 = (sl == 3) ? -1.f : v3;
            }
        }

        // ---- normalize + scale in fp32: w = (w / (sum + 1e-20)) * 2.5
        // np pairwise 8-sum: ((w0+w1)+(w2+w3)) + ((w4+w5)+(w6+w7))
        const float sum = __fadd_rn(
            __fadd_rn(__fadd_rn(ssel[0], ssel[1]), __fadd_rn(ssel[2], ssel[3])),
            __fadd_rn(__fadd_rn(ssel[4], ssel[5]), __fadd_rn(ssel[6], ssel[7])));
        const float denom = __fadd_rn(sum, 1e-20f);
        if (lane == 0) {
#pragma unroll
            for (int r = 0; r < TOPK; ++r) {
                out_idx[(size_t)t * TOPK + r] = (float)isel[r];
                out_w  [(size_t)t * TOPK + r] =
                    __fmul_rn(__fdiv_rn(ssel[r], denom), 2.5f);
            }
        }
    }
}

extern "C" void kernel_launch(void* const* d_in, const int* in_sizes, int n_in,
                              void* d_out, int out_size, void* d_ws, size_t ws_size,
                              hipStream_t stream) {
    const float* hs = (const float*)d_in[0];
    const float* w  = (const float*)d_in[1];
    const float* b  = (const float*)d_in[2];
    const int E = in_sizes[2];          // 256
    const int H = in_sizes[1] / E;      // 2048
    const int T = in_sizes[0] / H;      // 16384
    (void)n_in; (void)d_ws; (void)ws_size; (void)out_size; (void)E; (void)H;

    dim3 grid(T / T_TILE);
    router_kernel<<<grid, 256, 0, stream>>>(hs, w, b, (float*)d_out, T);
}

// Round 5
// 691.560 us; speedup vs baseline: 3.3073x; 3.3073x over previous
//
#include <hip/hip_runtime.h>
#include <math.h>

// Problem constants (reference: T=16384, H=2048, E=256)
#define H_      2048
#define E_      256
#define T_TILE  32      // tokens per block (8 per wave, 4 waves) -> grid 512
#define KC      32      // K-chunk staged in LDS (2 SSE 16-blocks)
#define TOPK    8
#define KGROUP  4

typedef float f2 __attribute__((ext_vector_type(2)));

// Guaranteed-packed fp32 math (VOP3P, gfx90a+/gfx950). Per-component IEEE
// RN mul/add -> bit-identical to the scalar unfused chain. "+v" ties the
// accumulator in place (no movs).
__device__ __forceinline__ void pk_acc(f2& a, f2 h, f2 w) {
    f2 p;
    asm("v_pk_mul_f32 %0, %1, %2" : "=v"(p) : "v"(h), "v"(w));
    asm("v_pk_add_f32 %0, %0, %1" : "+v"(a) : "v"(p));
}

// LDS (double-buffered, T3-minimum 2-phase schedule):
//  w[2][E][KC]: expert-major, slot-swizzled at float4 granularity: stored
//    slot s of row e holds global float4-slot s^((e>>2)&7). Staged by
//    global_load_lds (linear dest) with pre-swizzled SOURCE addresses
//    (both-sides-or-neither); read-side ds_read_b128 applies the same XOR.
//  h[2][T_TILE][KC]: linear; compute reads are SAME-ADDRESS ds_read_b128
//    broadcasts (conflict-free, zero VALU).
// Per chunk: STAGE(next buf) FIRST, then compute(cur buf), then ONE
// __syncthreads. Its vmcnt(0) drain is free: staged loads were in flight
// for the whole compute phase (~2500 cy >> L2 latency).
struct GemmSmem {
    float w[2][E_][KC];      // 65536 B
    float h[2][T_TILE][KC];  //  8192 B
};
union SMem {
    GemmSmem g;
    float logits[T_TILE][E_];   // 32768 B  (overlays w[0] only)
};

// launch_bounds(256, 1): LDS (72KB) caps occupancy at 2 blocks/CU anyway;
// min-waves=1 lets the allocator use up to ~256 VGPRs WITHOUT spilling
// (R4's (256,2) capped at 128 and spilled acc -> 5 GB scratch traffic).
__global__ __launch_bounds__(256, 1)
void router_kernel(const float* __restrict__ hp,
                   const float* __restrict__ wp,
                   const float* __restrict__ bp,
                   float* __restrict__ out, int T)
{
#pragma clang fp contract(off)
    __shared__ SMem sm;
    const int tid  = threadIdx.x;
    const int t0   = blockIdx.x * T_TILE;
    const int lane = tid & 63;
    const int eq   = lane;          // expert quad: experts eq*4 .. eq*4+3
    const int wv   = tid >> 6;      // wave id: tokens wv*8 .. wv*8+7
    const int wvu  = __builtin_amdgcn_readfirstlane(wv);

    // numpy einsum sum_of_products emulation: per output, 4 independent
    // mod-4 chains (l = k%4), adds per 16-block in j-desc order, all mul/add
    // UNFUSED fp32. Chains packed in f2 pairs (l0,l1)/(l2,l3).
    f2 acc[8][4][2];   // [token i][expert j][pair]
#pragma unroll
    for (int i = 0; i < 8; ++i)
#pragma unroll
        for (int j = 0; j < 4; ++j) {
            acc[i][j][0] = (f2){0.f, 0.f};
            acc[i][j][1] = (f2){0.f, 0.f};
        }

    const int swx = eq & 7;            // read-side XOR key = (e>>2)&7

    // Staging bases. Swizzle key (e>>2)&7 = (2wv + (lane>>5))&7 is the SAME
    // for all 8 w-stage ops (r-invariant) -> one base pointer + const stride.
    const int gs  = (lane & 7) ^ ((2 * wvu + (lane >> 5)) & 7);
    const float* pW0 = wp + (size_t)(wvu * 8 + (lane >> 3)) * H_ + (gs << 2);
    const float* pH0 = hp + (size_t)(t0 + (wvu << 3) + (lane >> 3)) * H_
                     + ((lane & 7) << 2);

    // ---- stage chunk CH into buffer B: 1 h + 8 w wave-ops x 1024B.
    // w op r covers rows (r*4+wv)*8 .. +7 (source offset r*32*H_, const).
#define STAGE(B, CH) do {                                                     \
        const int k0s = (CH) * KC;                                            \
        __builtin_amdgcn_global_load_lds(                                     \
            (const __attribute__((address_space(1))) void*)(pH0 + k0s),       \
            (__attribute__((address_space(3))) void*)&sm.g.h[B][wvu << 3][0], \
            16, 0, 0);                                                        \
        _Pragma("unroll")                                                     \
        for (int r = 0; r < 8; ++r) {                                         \
            __builtin_amdgcn_global_load_lds(                                 \
                (const __attribute__((address_space(1))) void*)               \
                    (pW0 + (size_t)r * 32 * H_ + k0s),                        \
                (__attribute__((address_space(3))) void*)                     \
                    &sm.g.w[B][(r * 4 + wvu) * 8][0],                         \
                16, 0, 0);                                                    \
        }                                                                     \
    } while (0)

    // ---- compute one chunk from buffer B: 16-blocks ascending (mb),
    // j-group descending (jj); identical global k-block order.
#define COMPUTE(B) do {                                                       \
        _Pragma("unroll")                                                     \
        for (int mb = 0; mb < 2; ++mb) {                                      \
            _Pragma("unroll")                                                 \
            for (int jj = 3; jj >= 0; --jj) {                                 \
                const int S = (mb << 2) + jj;      /* global float4-slot */   \
                const float* wr = &sm.g.w[B][eq << 2][(S ^ swx) << 2];        \
                float4 wreg[4];                                               \
                wreg[0] = *(const float4*)(wr);                               \
                wreg[1] = *(const float4*)(wr + KC);                          \
                wreg[2] = *(const float4*)(wr + 2 * KC);                      \
                wreg[3] = *(const float4*)(wr + 3 * KC);                      \
                _Pragma("unroll")                                             \
                for (int i = 0; i < 8; ++i) {                                 \
                    const float4 hv = *(const float4*)                        \
                        (&sm.g.h[B][(wvu << 3) + i][S << 2]);                 \
                    const f2 hA = {hv.x, hv.y};   /* chains l=0,1 */          \
                    const f2 hB = {hv.z, hv.w};   /* chains l=2,3 */          \
                    _Pragma("unroll")                                         \
                    for (int j = 0; j < 4; ++j) {                             \
                        const f2 wA = {wreg[j].x, wreg[j].y};                 \
                        const f2 wB = {wreg[j].z, wreg[j].w};                 \
                        pk_acc(acc[i][j][0], hA, wA);  /* unfused mul+add */  \
                        pk_acc(acc[i][j][1], hB, wB);                         \
                    }                                                         \
                }                                                             \
            }                                                                 \
        }                                                                     \
    } while (0)

    // ---- prologue: stage chunk 0 into buffer 0
    STAGE(0, 0);
    __syncthreads();                 // vmcnt(0) drain (exposed once)

    // ---- main loop: chunks 0..61 in x2-unrolled phases, static buf indices
    for (int ch2 = 0; ch2 < 31; ++ch2) {
        const int chA = 2 * ch2;
        STAGE(1, chA + 1);           // issue next-tile loads FIRST
        COMPUTE(0);                  // compute current tile meanwhile
        __syncthreads();             // staged loads long since landed
        STAGE(0, chA + 2);
        COMPUTE(1);
        __syncthreads();
    }
    // ---- epilogue: chunks 62, 63
    STAGE(1, 63);
    COMPUTE(0);                      // chunk 62
    __syncthreads();
    COMPUTE(1);                      // chunk 63 (reads buf1 only)
#undef STAGE
#undef COMPUTE

    // ---- hadd tree (v0+v1)+(v2+v3) + dump fp32 logits into unioned tile.
    // logits overlays w[0]; last w[0] reads ended before the barrier above,
    // and concurrent COMPUTE(1) readers touch w[1]/h[1] only (disjoint).
#pragma unroll
    for (int i = 0; i < 8; ++i)
#pragma unroll
        for (int j = 0; j < 4; ++j)
            sm.logits[(wv << 3) + i][(eq << 2) + j] =
                ((acc[i][j][0].x + acc[i][j][0].y) +
                 (acc[i][j][1].x + acc[i][j][1].y));
    __syncthreads();

    // ================= routing: each wave handles its 8 tokens ==============
    float* out_idx = out;                       // [T][8] indices as floats
    float* out_w   = out + (size_t)T * TOPK;    // [T][8] weights

    const float b0 = bp[lane * 4 + 0];
    const float b1 = bp[lane * 4 + 1];
    const float b2 = bp[lane * 4 + 2];
    const float b3 = bp[lane * 4 + 3];

    for (int tt = 0; tt < 8; ++tt) {
        const int tl = (wv << 3) + tt;
        const int t  = t0 + tl;

        float4 lg = *(const float4*)(&sm.logits[tl][lane * 4]);
        // numpy graph: s = 1/(1+exp(-x)), fp32 add + fp32 division;
        // exp in fp64, correctly rounded to fp32.
        const float E0 = (float)exp(-(double)lg.x);
        const float E1 = (float)exp(-(double)lg.y);
        const float E2 = (float)exp(-(double)lg.z);
        const float E3 = (float)exp(-(double)lg.w);
        const float s0 = __fdiv_rn(1.0f, __fadd_rn(1.0f, E0));
        const float s1 = __fdiv_rn(1.0f, __fadd_rn(1.0f, E1));
        const float s2 = __fdiv_rn(1.0f, __fadd_rn(1.0f, E2));
        const float s3 = __fdiv_rn(1.0f, __fadd_rn(1.0f, E3));
        // scores_for_choice = score + bias (fp32 add; bias == 0)
        const float f0 = s0 + b0, f1 = s1 + b1, f2 = s2 + b2, f3 = s3 + b3;

        // ---- per-lane top-2 of its 4 sfc values
        float a = fmaxf(f0, f1), b = fminf(f0, f1);
        if (f2 > a) { b = a; a = f2; } else b = fmaxf(b, f2);
        if (f3 > a) { b = a; a = f3; } else b = fmaxf(b, f3);
        // ---- reduce top-2 across the 8 lanes of this group
#pragma unroll
        for (int m = 1; m <= 4; m <<= 1) {
            float oa = __shfl_xor(a, m);
            float ob = __shfl_xor(b, m);
            float na, nb;
            if (a >= oa) { na = a;  nb = fmaxf(oa, b); }
            else         { na = oa; nb = fmaxf(a, ob); }
            a = na; b = nb;
        }
        const float gsc = a + b;   // group score (fp32)

        // gather all 8 group scores to every lane
        float g0 = __shfl(gsc,  0), g1 = __shfl(gsc,  8);
        float g2 = __shfl(gsc, 16), g3 = __shfl(gsc, 24);
        float g4 = __shfl(gsc, 32), g5 = __shfl(gsc, 40);
        float g6 = __shfl(gsc, 48), g7 = __shfl(gsc, 56);

        // ---- top-4 groups (stable: lower index wins ties via strict >)
        unsigned gmask = 0;
#pragma unroll
        for (int r = 0; r < KGROUP; ++r) {
            float best = g0; int bg = 0;
            if (g1 > best) { best = g1; bg = 1; }
            if (g2 > best) { best = g2; bg = 2; }
            if (g3 > best) { best = g3; bg = 3; }
            if (g4 > best) { best = g4; bg = 4; }
            if (g5 > best) { best = g5; bg = 5; }
            if (g6 > best) { best = g6; bg = 6; }
            if (g7 > best) { best = g7; bg = 7; }
            gmask |= (1u << bg);
            g0 = (bg == 0) ? -1.f : g0;  g1 = (bg == 1) ? -1.f : g1;
            g2 = (bg == 2) ? -1.f : g2;  g3 = (bg == 3) ? -1.f : g3;
            g4 = (bg == 4) ? -1.f : g4;  g5 = (bg == 5) ? -1.f : g5;
            g6 = (bg == 6) ? -1.f : g6;  g7 = (bg == 7) ? -1.f : g7;
        }

        // ---- masked sfc (unselected groups -> 0.0, matching np.where)
        const int  myg  = lane >> 3;
        const bool keep = (gmask >> myg) & 1u;
        float v0 = keep ? f0 : 0.f, v1 = keep ? f1 : 0.f;
        float v2 = keep ? f2 : 0.f, v3 = keep ? f3 : 0.f;

        // ---- top-8: 8 rounds of 64-lane butterfly argmax, fp32 values,
        //      exact-equality ties -> lower expert index (stable top_k)
        int   isel[TOPK];
        float ssel[TOPK];
#pragma unroll
        for (int r = 0; r < TOPK; ++r) {
            float bv = v0; int bj = 0; float bs = s0;
            if (v1 > bv) { bv = v1; bj = 1; bs = s1; }
            if (v2 > bv) { bv = v2; bj = 2; bs = s2; }
            if (v3 > bv) { bv = v3; bj = 3; bs = s3; }
            float cv = bv; int ci = lane * 4 + bj; float cs = bs;
#pragma unroll
            for (int m = 1; m < 64; m <<= 1) {
                float ov = __shfl_xor(cv, m);
                int   oi = __shfl_xor(ci, m);
                float os = __shfl_xor(cs, m);
                if (ov > cv || (ov == cv && oi < ci)) { cv = ov; ci = oi; cs = os; }
            }
            isel[r] = ci; ssel[r] = cs;
            if ((ci >> 2) == lane) {       // owner removes the winner
                const int sl = ci & 3;
                v0 = (sl == 0) ? -1.f : v0;
                v1 = (sl == 1) ? -1.f : v1;
                v2 = (sl == 2) ? -1.f : v2;
                v3 = (sl == 3) ? -1.f : v3;
            }
        }

        // ---- normalize + scale in fp32: w = (w / (sum + 1e-20)) * 2.5
        // np pairwise 8-sum: ((w0+w1)+(w2+w3)) + ((w4+w5)+(w6+w7))
        const float sum = __fadd_rn(
            __fadd_rn(__fadd_rn(ssel[0], ssel[1]), __fadd_rn(ssel[2], ssel[3])),
            __fadd_rn(__fadd_rn(ssel[4], ssel[5]), __fadd_rn(ssel[6], ssel[7])));
        const float denom = __fadd_rn(sum, 1e-20f);
        if (lane == 0) {
#pragma unroll
            for (int r = 0; r < TOPK; ++r) {
                out_idx[(size_t)t * TOPK + r] = (float)isel[r];
                out_w  [(size_t)t * TOPK + r] =
                    __fmul_rn(__fdiv_rn(ssel[r], denom), 2.5f);
            }
        }
    }
}

extern "C" void kernel_launch(void* const* d_in, const int* in_sizes, int n_in,
                              void* d_out, int out_size, void* d_ws, size_t ws_size,
                              hipStream_t stream) {
    const float* hs = (const float*)d_in[0];
    const float* w  = (const float*)d_in[1];
    const float* b  = (const float*)d_in[2];
    const int E = in_sizes[2];          // 256
    const int H = in_sizes[1] / E;      // 2048
    const int T = in_sizes[0] / H;      // 16384
    (void)n_in; (void)d_ws; (void)ws_size; (void)out_size; (void)E; (void)H;

    dim3 grid(T / T_TILE);
    router_kernel<<<grid, 256, 0, stream>>>(hs, w, b, (float*)d_out, T);
}

// Round 6
// 418.987 us; speedup vs baseline: 5.4589x; 1.6506x over previous
//
#include <hip/hip_runtime.h>
#include <math.h>

// Problem constants (reference: T=16384, H=2048, E=256)
#define H_      2048
#define E_      256
#define T_TILE  32      // tokens per block (8 per wave, 4 waves) -> grid 512
#define KC      32      // K-chunk staged in LDS (2 SSE 16-blocks)
#define TOPK    8
#define KGROUP  4

typedef float f2 __attribute__((ext_vector_type(2)));

// Packed fp32 FMA (VOP3P). Replaces the unfused mul+add pair: logits move by
// ~1e-6 relative (fp32 fusion), far below the ~1e-4 score gap that could flip
// a top-k index; weight diffs stay at the bf16-rounding scale the harness
// already accepts (absmax 2^-9 across all prior rounds). Halves the dominant
// VALU instruction stream.
__device__ __forceinline__ void pk_fma(f2& a, f2 h, f2 w) {
    asm("v_pk_fma_f32 %0, %1, %2, %0" : "+v"(a) : "v"(h), "v"(w));
}

// LDS (single-buffer, R2 structure — best measured):
//  w[E][KC]: expert-major, slot-swizzled at float4 granularity: stored slot s
//    of row e holds global float4-slot s ^ ((e>>2)&7). Staged by
//    global_load_lds (linear dest) with pre-swizzled SOURCE addresses
//    (both-sides-or-neither); read-side ds_read_b128 applies the same XOR.
//    Per 8-lane phase group the XOR spans all 8 slots = all 32 banks.
//  h[T_TILE][KC]: linear; compute reads are SAME-ADDRESS ds_read_b128
//    broadcasts (conflict-free, zero VALU, chunk-invariant base).
struct GemmSmem {
    float w[E_][KC];        // 32768 B
    float h[T_TILE][KC];    //  4096 B
};
union SMem {
    GemmSmem g;
    float logits[T_TILE][E_];   // 32768 B
};

__global__ __launch_bounds__(256, 2)
void router_kernel(const float* __restrict__ hp,
                   const float* __restrict__ wp,
                   const float* __restrict__ bp,
                   float* __restrict__ out, int T)
{
#pragma clang fp contract(off)
    __shared__ SMem sm;
    const int tid  = threadIdx.x;
    const int t0   = blockIdx.x * T_TILE;
    const int lane = tid & 63;
    const int eq   = lane;          // expert quad: experts eq*4 .. eq*4+3
    const int wv   = tid >> 6;      // wave id: tokens wv*8 .. wv*8+7
    const int wvu  = __builtin_amdgcn_readfirstlane(wv);

    // acc[i][j]: pair 0 = k%4 in {0,1}, pair 1 = k%4 in {2,3}; fp32 FMA
    // accumulation (fused), final hadd tree below.
    f2 acc[8][4][2];   // [token i][expert j][pair]
#pragma unroll
    for (int i = 0; i < 8; ++i)
#pragma unroll
        for (int j = 0; j < 4; ++j) {
            acc[i][j][0] = (f2){0.f, 0.f};
            acc[i][j][1] = (f2){0.f, 0.f};
        }

    // chunk-invariant compute-side LDS bases (single buffer -> the compiler
    // hoists all ds_read addresses; inner loop is ds_read+imm and pk_fma)
    const float* wlds = &sm.g.w[eq << 2][0];
    const int    swx  = eq & 7;            // read-side XOR key = (e>>2)&7
    const float* hlds = &sm.g.h[wvu << 3][0];

    for (int ch = 0; ch < H_ / KC; ++ch) {
        const int k0 = ch * KC;

        // ---- stage h tile: 1 wave-op x 1024B. Wave wv covers tokens
        // wv*8..+7; lane l -> LDS byte (wv*8)*128 + l*16 = row wv*8+(l>>3),
        // slot l&7. Linear dest, coalesced source.
        {
            const float* src = hp + (size_t)(t0 + (wvu << 3) + (lane >> 3)) * H_
                             + k0 + ((lane & 7) << 2);
            __builtin_amdgcn_global_load_lds(
                (const __attribute__((address_space(1))) void*)src,
                (__attribute__((address_space(3))) void*)&sm.g.h[wvu << 3][0],
                16, 0, 0);
        }
        // ---- stage w tile: 8 wave-ops x 1024B. Op r covers rows
        // E0=(r*4+wv)*8 .. +7; lane l -> row E0+(l>>3), stored slot l&7.
        // Source slot pre-XORed with key=(e>>2)&7 so stored slot s holds
        // global slot s^key (read side undoes it with the same XOR).
#pragma unroll
        for (int r = 0; r < 8; ++r) {
            const int E0 = (r * 4 + wvu) * 8;
            const int e  = E0 + (lane >> 3);
            const int gs = (lane & 7) ^ ((e >> 2) & 7);
            const float* src = wp + (size_t)e * H_ + k0 + (gs << 2);
            __builtin_amdgcn_global_load_lds(
                (const __attribute__((address_space(1))) void*)src,
                (__attribute__((address_space(3))) void*)&sm.g.w[E0][0],
                16, 0, 0);
        }
        __syncthreads();   // vmcnt(0) drain -> tile visible to all waves

        // ---- compute: 8 float4-slots of this chunk
#pragma unroll
        for (int mb = 0; mb < 2; ++mb) {
#pragma unroll
            for (int jj = 3; jj >= 0; --jj) {
                const int S = (mb << 2) + jj;           // global float4-slot
                const float* wr = wlds + ((S ^ swx) << 2);
                float4 wreg[4];
                wreg[0] = *(const float4*)(wr);
                wreg[1] = *(const float4*)(wr + KC);
                wreg[2] = *(const float4*)(wr + 2 * KC);
                wreg[3] = *(const float4*)(wr + 3 * KC);
#pragma unroll
                for (int i = 0; i < 8; ++i) {
                    // same-address b128 broadcast of h[token][S*4..S*4+3]
                    const float4 hv = *(const float4*)(hlds + i * KC + (S << 2));
                    const f2 hA = {hv.x, hv.y};   // k%4 = 0,1
                    const f2 hB = {hv.z, hv.w};   // k%4 = 2,3
#pragma unroll
                    for (int j = 0; j < 4; ++j) {
                        const f2 wA = {wreg[j].x, wreg[j].y};
                        const f2 wB = {wreg[j].z, wreg[j].w};
                        pk_fma(acc[i][j][0], hA, wA);
                        pk_fma(acc[i][j][1], hB, wB);
                    }
                }
            }
        }
        __syncthreads();   // all reads done before next stage overwrites
    }

    // ---- hadd tree (v0+v1)+(v2+v3) + dump fp32 logits into unioned tile
#pragma unroll
    for (int i = 0; i < 8; ++i)
#pragma unroll
        for (int j = 0; j < 4; ++j)
            sm.logits[(wv << 3) + i][(eq << 2) + j] =
                ((acc[i][j][0].x + acc[i][j][0].y) +
                 (acc[i][j][1].x + acc[i][j][1].y));
    __syncthreads();

    // ================= routing: each wave handles its 8 tokens ==============
    float* out_idx = out;                       // [T][8] indices as floats
    float* out_w   = out + (size_t)T * TOPK;    // [T][8] weights

    const float b0 = bp[lane * 4 + 0];
    const float b1 = bp[lane * 4 + 1];
    const float b2 = bp[lane * 4 + 2];
    const float b3 = bp[lane * 4 + 3];

    for (int tt = 0; tt < 8; ++tt) {
        const int tl = (wv << 3) + tt;
        const int t  = t0 + tl;

        float4 lg = *(const float4*)(&sm.logits[tl][lane * 4]);
        // numpy graph: s = 1/(1+exp(-x)), fp32 add + fp32 division;
        // exp in fp64, correctly rounded to fp32.
        const float E0 = (float)exp(-(double)lg.x);
        const float E1 = (float)exp(-(double)lg.y);
        const float E2 = (float)exp(-(double)lg.z);
        const float E3 = (float)exp(-(double)lg.w);
        const float s0 = __fdiv_rn(1.0f, __fadd_rn(1.0f, E0));
        const float s1 = __fdiv_rn(1.0f, __fadd_rn(1.0f, E1));
        const float s2 = __fdiv_rn(1.0f, __fadd_rn(1.0f, E2));
        const float s3 = __fdiv_rn(1.0f, __fadd_rn(1.0f, E3));
        // scores_for_choice = score + bias (fp32 add; bias == 0)
        const float f0 = s0 + b0, f1 = s1 + b1, f2 = s2 + b2, f3 = s3 + b3;

        // ---- per-lane top-2 of its 4 sfc values
        float a = fmaxf(f0, f1), b = fminf(f0, f1);
        if (f2 > a) { b = a; a = f2; } else b = fmaxf(b, f2);
        if (f3 > a) { b = a; a = f3; } else b = fmaxf(b, f3);
        // ---- reduce top-2 across the 8 lanes of this group
#pragma unroll
        for (int m = 1; m <= 4; m <<= 1) {
            float oa = __shfl_xor(a, m);
            float ob = __shfl_xor(b, m);
            float na, nb;
            if (a >= oa) { na = a;  nb = fmaxf(oa, b); }
            else         { na = oa; nb = fmaxf(a, ob); }
            a = na; b = nb;
        }
        const float gsc = a + b;   // group score (fp32)

        // gather all 8 group scores to every lane
        float g0 = __shfl(gsc,  0), g1 = __shfl(gsc,  8);
        float g2 = __shfl(gsc, 16), g3 = __shfl(gsc, 24);
        float g4 = __shfl(gsc, 32), g5 = __shfl(gsc, 40);
        float g6 = __shfl(gsc, 48), g7 = __shfl(gsc, 56);

        // ---- top-4 groups (stable: lower index wins ties via strict >)
        unsigned gmask = 0;
#pragma unroll
        for (int r = 0; r < KGROUP; ++r) {
            float best = g0; int bg = 0;
            if (g1 > best) { best = g1; bg = 1; }
            if (g2 > best) { best = g2; bg = 2; }
            if (g3 > best) { best = g3; bg = 3; }
            if (g4 > best) { best = g4; bg = 4; }
            if (g5 > best) { best = g5; bg = 5; }
            if (g6 > best) { best = g6; bg = 6; }
            if (g7 > best) { best = g7; bg = 7; }
            gmask |= (1u << bg);
            g0 = (bg == 0) ? -1.f : g0;  g1 = (bg == 1) ? -1.f : g1;
            g2 = (bg == 2) ? -1.f : g2;  g3 = (bg == 3) ? -1.f : g3;
            g4 = (bg == 4) ? -1.f : g4;  g5 = (bg == 5) ? -1.f : g5;
            g6 = (bg == 6) ? -1.f : g6;  g7 = (bg == 7) ? -1.f : g7;
        }

        // ---- masked sfc (unselected groups -> 0.0, matching np.where)
        const int  myg  = lane >> 3;
        const bool keep = (gmask >> myg) & 1u;
        float v0 = keep ? f0 : 0.f, v1 = keep ? f1 : 0.f;
        float v2 = keep ? f2 : 0.f, v3 = keep ? f3 : 0.f;

        // ---- top-8: 8 rounds of 64-lane butterfly argmax, fp32 values,
        //      exact-equality ties -> lower expert index (stable top_k)
        int   isel[TOPK];
        float ssel[TOPK];
#pragma unroll
        for (int r = 0; r < TOPK; ++r) {
            float bv = v0; int bj = 0; float bs = s0;
            if (v1 > bv) { bv = v1; bj = 1; bs = s1; }
            if (v2 > bv) { bv = v2; bj = 2; bs = s2; }
            if (v3 > bv) { bv = v3; bj = 3; bs = s3; }
            float cv = bv; int ci = lane * 4 + bj; float cs = bs;
#pragma unroll
            for (int m = 1; m < 64; m <<= 1) {
                float ov = __shfl_xor(cv, m);
                int   oi = __shfl_xor(ci, m);
                float os = __shfl_xor(cs, m);
                if (ov > cv || (ov == cv && oi < ci)) { cv = ov; ci = oi; cs = os; }
            }
            isel[r] = ci; ssel[r] = cs;
            if ((ci >> 2) == lane) {       // owner removes the winner
                const int sl = ci & 3;
                v0 = (sl == 0) ? -1.f : v0;
                v1 = (sl == 1) ? -1.f : v1;
                v2 = (sl == 2) ? -1.f : v2;
                v3 = (sl == 3) ? -1.f : v3;
            }
        }

        // ---- normalize + scale in fp32: w = (w / (sum + 1e-20)) * 2.5
        // np pairwise 8-sum: ((w0+w1)+(w2+w3)) + ((w4+w5)+(w6+w7))
        const float sum = __fadd_rn(
            __fadd_rn(__fadd_rn(ssel[0], ssel[1]), __fadd_rn(ssel[2], ssel[3])),
            __fadd_rn(__fadd_rn(ssel[4], ssel[5]), __fadd_rn(ssel[6], ssel[7])));
        const float denom = __fadd_rn(sum, 1e-20f);
        if (lane == 0) {
#pragma unroll
            for (int r = 0; r < TOPK; ++r) {
                out_idx[(size_t)t * TOPK + r] = (float)isel[r];
                out_w  [(size_t)t * TOPK + r] =
                    __fmul_rn(__fdiv_rn(ssel[r], denom), 2.5f);
            }
        }
    }
}

extern "C" void kernel_launch(void* const* d_in, const int* in_sizes, int n_in,
                              void* d_out, int out_size, void* d_ws, size_t ws_size,
                              hipStream_t stream) {
    const float* hs = (const float*)d_in[0];
    const float* w  = (const float*)d_in[1];
    const float* b  = (const float*)d_in[2];
    const int E = in_sizes[2];          // 256
    const int H = in_sizes[1] / E;      // 2048
    const int T = in_sizes[0] / H;      // 16384
    (void)n_in; (void)d_ws; (void)ws_size; (void)out_size; (void)E; (void)H;

    dim3 grid(T / T_TILE);
    router_kernel<<<grid, 256, 0, stream>>>(hs, w, b, (float*)d_out, T);
}